// Round 4
// baseline (258.661 us; speedup 1.0000x reference)
//
#include <hip/hip_runtime.h>
#include <math.h>

#define BB 64
#define SS 512
#define HH 768
#define AA1 100
#define CC1 300

typedef __bf16 bf16x8 __attribute__((ext_vector_type(8)));
typedef float f32x4 __attribute__((ext_vector_type(4)));

#ifndef __has_builtin
#define __has_builtin(x) 0
#endif
#if __has_builtin(__builtin_amdgcn_global_load_lds)
#define HAVE_GLL 1
#else
#define HAVE_GLL 0
#endif

#define AS1 __attribute__((address_space(1)))
#define AS3 __attribute__((address_space(3)))

// ---------------------------------------------------------------------------
// Prep: B image for async staging. Per K-tile kt (32 k), chunk-major layout:
//   w1i[((kt*4+q)*112 + j)*8 + e] = bf16(w1[(kt*32+q*8+e)*100 + j]), 0-pad j>=100
// So each K-iter's B tile is one contiguous 7168-B region; fragment reads from
// LDS are [q][j] chunk-major -> 2-way bank aliasing only (free).
// ---------------------------------------------------------------------------
__global__ __launch_bounds__(256) void k_prep(const float* __restrict__ w1,
                                              __bf16* __restrict__ w1i) {
    int idx = blockIdx.x * 256 + threadIdx.x;   // 96*8*112 = 86016 = 336*256
    int j = idx % 112;
    int r = idx / 112;          // g*8 + e
    int e = r & 7, g = r >> 3;  // g = kt*4 + q
    int k = (g >> 2) * 32 + (g & 3) * 8 + e;
    float v = (j < AA1) ? w1[k * AA1 + j] : 0.f;
    w1i[((size_t)g * 112 + j) * 8 + e] = (__bf16)v;
}

// ---------------------------------------------------------------------------
// Kernel 1: token attention via bf16 MFMA 16x16x32, async global->LDS staging.
// 64 tokens/block, N=112 (7 tiles), K-loop 24 x 32.
// A staged as fp32 with XOR chunk swizzle (pos = c ^ (t&7)); converted to bf16
// at fragment read. B staged verbatim from the k_prep image.
// ---------------------------------------------------------------------------
__global__ __launch_bounds__(256) void k_token_att(
        const float* __restrict__ hs, const __bf16* __restrict__ w1i,
        const float* __restrict__ b1, const float* __restrict__ w2,
        const float* __restrict__ b2, float* __restrict__ token_att) {
    __shared__ __attribute__((aligned(16))) float lA[2048];   // 64 tok x 32 k fp32
    __shared__ __attribute__((aligned(16))) __bf16 lB[3584];  // [q][j] chunks

    const int tid = threadIdx.x;
    const int tok0 = blockIdx.x * 64;
    const int w = tid >> 6, lane = tid & 63;
    const int q = lane >> 4, ln = lane & 15;
    const int t = w * 16 + ln;

    f32x4 acc[7];
#pragma unroll
    for (int n = 0; n < 7; n++) acc[n] = (f32x4){0.f, 0.f, 0.f, 0.f};

    const int p0 = (2 * q) ^ (ln & 7);
    const int p1 = (2 * q + 1) ^ (ln & 7);

    for (int kt = 0; kt < 24; kt++) {
        const int ko = kt * 32;
        // ---- A: 512 chunks (16B), chunk i holds token i>>3, global chunk (i&7)^(t&7)
        {
            int i0 = tid;
            int t0 = i0 >> 3, c0 = (i0 & 7) ^ (t0 & 7);
            const float* g0 = hs + (size_t)(tok0 + t0) * HH + ko + c0 * 4;
            int i1 = tid + 256;
            int t1 = i1 >> 3, c1 = (i1 & 7) ^ (t1 & 7);
            const float* g1 = hs + (size_t)(tok0 + t1) * HH + ko + c1 * 4;
            const __bf16* gb0 = w1i + (size_t)kt * 3584 + (size_t)tid * 8;
#if HAVE_GLL
            __builtin_amdgcn_global_load_lds((AS1 void*)g0,
                    (AS3 void*)(lA + (w * 64) * 4), 16, 0, 0);
            __builtin_amdgcn_global_load_lds((AS1 void*)g1,
                    (AS3 void*)(lA + (256 + w * 64) * 4), 16, 0, 0);
            __builtin_amdgcn_global_load_lds((AS1 void*)gb0,
                    (AS3 void*)(lB + (w * 64) * 8), 16, 0, 0);
            if (w < 3) {
                const __bf16* gb1 = w1i + (size_t)kt * 3584 + (size_t)(tid + 256) * 8;
                __builtin_amdgcn_global_load_lds((AS1 void*)gb1,
                        (AS3 void*)(lB + (256 + w * 64) * 8), 16, 0, 0);
            }
#else
            *(f32x4*)&lA[i0 * 4] = *(const f32x4*)g0;
            *(f32x4*)&lA[i1 * 4] = *(const f32x4*)g1;
            *(bf16x8*)&lB[(size_t)tid * 8] = *(const bf16x8*)gb0;
            if (tid < 192) {
                const __bf16* gb1 = w1i + (size_t)kt * 3584 + (size_t)(tid + 256) * 8;
                *(bf16x8*)&lB[(size_t)(tid + 256) * 8] = *(const bf16x8*)gb1;
            }
#endif
        }
        __syncthreads();
        // ---- A fragment: token t, k-range q*8..q*8+7, fp32 -> bf16
        f32x4 a0 = *(f32x4*)&lA[(t * 8 + p0) * 4];
        f32x4 a1 = *(f32x4*)&lA[(t * 8 + p1) * 4];
        bf16x8 af;
        af[0] = (__bf16)a0[0]; af[1] = (__bf16)a0[1];
        af[2] = (__bf16)a0[2]; af[3] = (__bf16)a0[3];
        af[4] = (__bf16)a1[0]; af[5] = (__bf16)a1[1];
        af[6] = (__bf16)a1[2]; af[7] = (__bf16)a1[3];
#pragma unroll
        for (int n = 0; n < 7; n++) {
            bf16x8 bf = *(bf16x8*)&lB[((size_t)q * 112 + n * 16 + ln) * 8];
            acc[n] = __builtin_amdgcn_mfma_f32_16x16x32_bf16(af, bf, acc[n], 0, 0, 0);
        }
        __syncthreads();
    }

    // epilogue: C/D layout col=lane&15 (unit j), row=quad*4+reg (token)
    float s0 = 0.f, s1 = 0.f, s2 = 0.f, s3 = 0.f;
#pragma unroll
    for (int n = 0; n < 7; n++) {
        int j = n * 16 + ln;
        if (j < AA1) {
            float bj = b1[j], wj = w2[j];
            s0 += tanhf(acc[n][0] + bj) * wj;
            s1 += tanhf(acc[n][1] + bj) * wj;
            s2 += tanhf(acc[n][2] + bj) * wj;
            s3 += tanhf(acc[n][3] + bj) * wj;
        }
    }
#pragma unroll
    for (int off = 1; off < 16; off <<= 1) {
        s0 += __shfl_xor(s0, off);
        s1 += __shfl_xor(s1, off);
        s2 += __shfl_xor(s2, off);
        s3 += __shfl_xor(s3, off);
    }
    if (ln == 0) {
        float bb = b2[0];
        int base = tok0 + w * 16 + q * 4;
        token_att[base + 0] = 1.f / (1.f + expf(-(s0 + bb)));
        token_att[base + 1] = 1.f / (1.f + expf(-(s1 + bb)));
        token_att[base + 2] = 1.f / (1.f + expf(-(s2 + bb)));
        token_att[base + 3] = 1.f / (1.f + expf(-(s3 + bb)));
    }
}

// ---------------------------------------------------------------------------
// Kernel 2 (fused tail): scan/segmax/mask + reductions + nonzero compaction +
// pooling + sentence MLP + per-row loss contributions (atomicAdd into out[0..5)).
// One block (512 threads) per batch row.
// ---------------------------------------------------------------------------
__global__ __launch_bounds__(512) void k_tail(
        const float* __restrict__ hs, const float* __restrict__ token_att,
        const float* __restrict__ labels, const int* __restrict__ offm,
        const float* __restrict__ sw1, const float* __restrict__ sb1,
        const float* __restrict__ sw2, const float* __restrict__ sb2,
        float* __restrict__ masked_out, float* __restrict__ sent_out,
        float* __restrict__ out) {
    __shared__ int smax[512];
    __shared__ int wscan[8];
    __shared__ int wscan2[8];
    __shared__ float wred[5][8];
    __shared__ float cw[512];
    __shared__ short cs[512];
    __shared__ float pool[HH];
    __shared__ float wsum[8];

    const int b = blockIdx.x, s = threadIdx.x;
    const int lane = s & 63, wv = s >> 6;
    const int ns = (offm[(b * SS + s) * 2] == 0) ? 1 : 0;

    // ---- inclusive scan of word-starts -> segment id
    int v = ns;
#pragma unroll
    for (int off = 1; off < 64; off <<= 1) {
        int o = __shfl_up(v, off);
        if (lane >= off) v += o;
    }
    if (lane == 63) wscan[wv] = v;
    smax[s] = 0;
    __syncthreads();
    int woff = 0;
    for (int i = 0; i < 8; i++) woff += (i < wv) ? wscan[i] : 0;
    const int seg = max(v + woff - 1, 0);

    const float ta = token_att[b * SS + s];
    atomicMax(&smax[seg], __float_as_int(ta));   // sigmoid > 0: int order ok
    __syncthreads();

    const float wa = ns ? __int_as_float(smax[seg]) : 0.f;
    const float lab = labels[b * SS + s];
    const float m = (lab != -1.f && ns) ? wa : 0.f;
    masked_out[b * SS + s] = m;

    const float zl = (lab != -1.f) ? lab : 0.f;
    const float tl = (m - zl) * (m - zl);
    const float ones = (m == 0.f) ? 1.f : m;

    // ---- 5 block reductions (wave shuffle + LDS)
    float r0 = m, r1 = tl, r2 = m, r3 = ones, r4 = lab;
#pragma unroll
    for (int off = 32; off > 0; off >>= 1) {
        r0 += __shfl_xor(r0, off);
        r1 += __shfl_xor(r1, off);
        r2 = fmaxf(r2, __shfl_xor(r2, off));
        r3 = fminf(r3, __shfl_xor(r3, off));
        r4 = fmaxf(r4, __shfl_xor(r4, off));
    }
    if (lane == 0) {
        wred[0][wv] = r0; wred[1][wv] = r1; wred[2][wv] = r2;
        wred[3][wv] = r3; wred[4][wv] = r4;
    }

    // ---- compaction scan over nonzero masked
    const int nz = (m != 0.f) ? 1 : 0;
    int v2 = nz;
#pragma unroll
    for (int off = 1; off < 64; off <<= 1) {
        int o = __shfl_up(v2, off);
        if (lane >= off) v2 += o;
    }
    if (lane == 63) wscan2[wv] = v2;
    __syncthreads();

    float att = 0.f, tokl = 0.f, maxm = -1e30f, minone = 1e30f, slab = -1e30f;
    for (int i = 0; i < 8; i++) {
        att += wred[0][i]; tokl += wred[1][i];
        maxm = fmaxf(maxm, wred[2][i]);
        minone = fminf(minone, wred[3][i]);
        slab = fmaxf(slab, wred[4][i]);
    }
    int woff2 = 0, nnz = 0;
    for (int i = 0; i < 8; i++) {
        woff2 += (i < wv) ? wscan2[i] : 0;
        nnz += wscan2[i];
    }
    if (nz) {
        int pos = v2 + woff2 - 1;
        cw[pos] = m;
        cs[pos] = (short)s;
    }
    __syncthreads();

    // ---- pooling over compacted list (h = s, and h = 512+s for s<256)
    const float inv = 1.f / att;
    float a0 = 0.f, a1 = 0.f;
    const float* hsb = hs + (size_t)b * SS * HH;
    for (int i = 0; i < nnz; i++) {
        const float wv_ = cw[i];
        const float* hp = hsb + (size_t)cs[i] * HH;
        a0 += hp[s] * wv_;
        if (s < 256) a1 += hp[s + 512] * wv_;
    }
    pool[s] = a0 * inv;
    if (s < 256) pool[s + 512] = a1 * inv;
    __syncthreads();

    // ---- sentence MLP: thread = hidden unit (s < 300)
    float tt = 0.f;
    if (s < CC1) {
        float z = sb1[s];
#pragma unroll 8
        for (int k = 0; k < HH; k++) z += pool[k] * sw1[k * CC1 + s];
        tt = tanhf(z) * sw2[s];
    }
#pragma unroll
    for (int off = 32; off > 0; off >>= 1) tt += __shfl_xor(tt, off);
    if (lane == 0) wsum[wv] = tt;
    __syncthreads();

    if (s == 0) {
        float zsum = 0.f;
        for (int i = 0; i < 8; i++) zsum += wsum[i];
        float sv = 1.f / (1.f + expf(-(zsum + sb2[0])));
        sent_out[b] = sv;
        float vs = sv - slab; vs *= vs;
        float ra = minone * minone;
        float rb = maxm - slab; rb *= rb;
        atomicAdd(&out[1], vs);
        atomicAdd(&out[2], tokl);
        atomicAdd(&out[3], ra);
        atomicAdd(&out[4], rb);
        atomicAdd(&out[0], vs + tokl + 0.01f * (ra + rb));
    }
}

extern "C" void kernel_launch(void* const* d_in, const int* in_sizes, int n_in,
                              void* d_out, int out_size, void* d_ws, size_t ws_size,
                              hipStream_t stream) {
    const float* hs  = (const float*)d_in[0];
    const float* w1  = (const float*)d_in[1];
    const float* b1  = (const float*)d_in[2];
    const float* w2  = (const float*)d_in[3];
    const float* b2  = (const float*)d_in[4];
    const float* sw1 = (const float*)d_in[5];
    const float* sb1 = (const float*)d_in[6];
    const float* sw2 = (const float*)d_in[7];
    const float* sb2 = (const float*)d_in[8];
    const float* labels = (const float*)d_in[9];
    const int*   offm   = (const int*)d_in[10];

    float* out = (float*)d_out;
    float* ws  = (float*)d_ws;

    // ws layout (float units)
    float*  token_att = ws;                     // 32768 floats
    __bf16* w1i       = (__bf16*)(ws + 32768);  // 86016 bf16

    // d_out layout: [total, sentence_loss, token_loss, reg_a, reg_b,
    //                masked(64*512), sent(64)]
    float* masked_out = out + 5;
    float* sent_out   = out + 5 + BB * SS;

    hipMemsetAsync(out, 0, 5 * sizeof(float), stream);   // atomicAdd targets
    hipLaunchKernelGGL(k_prep, dim3(336), dim3(256), 0, stream, w1, w1i);
    hipLaunchKernelGGL(k_token_att, dim3(512), dim3(256), 0, stream,
                       hs, w1i, b1, w2, b2, token_att);
    hipLaunchKernelGGL(k_tail, dim3(BB), dim3(512), 0, stream,
                       hs, token_att, labels, offm, sw1, sb1, sw2, sb2,
                       masked_out, sent_out, out);
}

// Round 5
// 246.874 us; speedup vs baseline: 1.0477x; 1.0477x over previous
//
#include <hip/hip_runtime.h>
#include <math.h>

#define BB 64
#define SS 512
#define HH 768
#define AA1 100
#define CC1 300

typedef __bf16 bf16x8 __attribute__((ext_vector_type(8)));
typedef float f32x4 __attribute__((ext_vector_type(4)));

#ifndef __has_builtin
#define __has_builtin(x) 0
#endif
#if __has_builtin(__builtin_amdgcn_global_load_lds)
#define HAVE_GLL 1
#else
#define HAVE_GLL 0
#endif

#define AS1 __attribute__((address_space(1)))
#define AS3 __attribute__((address_space(3)))

// ---------------------------------------------------------------------------
// Prep: B image for async staging (chunk-major per 32-K tile, zero-pad j>=100)
// ---------------------------------------------------------------------------
__global__ __launch_bounds__(256) void k_prep(const float* __restrict__ w1,
                                              __bf16* __restrict__ w1i) {
    int idx = blockIdx.x * 256 + threadIdx.x;   // 96*8*112 = 86016 = 336*256
    int j = idx % 112;
    int r = idx / 112;          // g*8 + e
    int e = r & 7, g = r >> 3;  // g = kt*4 + q
    int k = (g >> 2) * 32 + (g & 3) * 8 + e;
    float v = (j < AA1) ? w1[k * AA1 + j] : 0.f;
    w1i[((size_t)g * 112 + j) * 8 + e] = (__bf16)v;
}

// ---------------------------------------------------------------------------
// Kernel 1: token attention via bf16 MFMA 16x16x32, async global->LDS staging.
// ---------------------------------------------------------------------------
__global__ __launch_bounds__(256) void k_token_att(
        const float* __restrict__ hs, const __bf16* __restrict__ w1i,
        const float* __restrict__ b1, const float* __restrict__ w2,
        const float* __restrict__ b2, float* __restrict__ token_att) {
    __shared__ __attribute__((aligned(16))) float lA[2048];   // 64 tok x 32 k fp32
    __shared__ __attribute__((aligned(16))) __bf16 lB[3584];  // [q][j] chunks

    const int tid = threadIdx.x;
    const int tok0 = blockIdx.x * 64;
    const int w = tid >> 6, lane = tid & 63;
    const int q = lane >> 4, ln = lane & 15;
    const int t = w * 16 + ln;

    f32x4 acc[7];
#pragma unroll
    for (int n = 0; n < 7; n++) acc[n] = (f32x4){0.f, 0.f, 0.f, 0.f};

    const int p0 = (2 * q) ^ (ln & 7);
    const int p1 = (2 * q + 1) ^ (ln & 7);

    for (int kt = 0; kt < 24; kt++) {
        const int ko = kt * 32;
        {
            int i0 = tid;
            int t0 = i0 >> 3, c0 = (i0 & 7) ^ (t0 & 7);
            const float* g0 = hs + (size_t)(tok0 + t0) * HH + ko + c0 * 4;
            int i1 = tid + 256;
            int t1 = i1 >> 3, c1 = (i1 & 7) ^ (t1 & 7);
            const float* g1 = hs + (size_t)(tok0 + t1) * HH + ko + c1 * 4;
            const __bf16* gb0 = w1i + (size_t)kt * 3584 + (size_t)tid * 8;
#if HAVE_GLL
            __builtin_amdgcn_global_load_lds((AS1 void*)g0,
                    (AS3 void*)(lA + (w * 64) * 4), 16, 0, 0);
            __builtin_amdgcn_global_load_lds((AS1 void*)g1,
                    (AS3 void*)(lA + (256 + w * 64) * 4), 16, 0, 0);
            __builtin_amdgcn_global_load_lds((AS1 void*)gb0,
                    (AS3 void*)(lB + (w * 64) * 8), 16, 0, 0);
            if (w < 3) {
                const __bf16* gb1 = w1i + (size_t)kt * 3584 + (size_t)(tid + 256) * 8;
                __builtin_amdgcn_global_load_lds((AS1 void*)gb1,
                        (AS3 void*)(lB + (256 + w * 64) * 8), 16, 0, 0);
            }
#else
            *(f32x4*)&lA[i0 * 4] = *(const f32x4*)g0;
            *(f32x4*)&lA[i1 * 4] = *(const f32x4*)g1;
            *(bf16x8*)&lB[(size_t)tid * 8] = *(const bf16x8*)gb0;
            if (tid < 192) {
                const __bf16* gb1 = w1i + (size_t)kt * 3584 + (size_t)(tid + 256) * 8;
                *(bf16x8*)&lB[(size_t)(tid + 256) * 8] = *(const bf16x8*)gb1;
            }
#endif
        }
        __syncthreads();
        f32x4 a0 = *(f32x4*)&lA[(t * 8 + p0) * 4];
        f32x4 a1 = *(f32x4*)&lA[(t * 8 + p1) * 4];
        bf16x8 af;
        af[0] = (__bf16)a0[0]; af[1] = (__bf16)a0[1];
        af[2] = (__bf16)a0[2]; af[3] = (__bf16)a0[3];
        af[4] = (__bf16)a1[0]; af[5] = (__bf16)a1[1];
        af[6] = (__bf16)a1[2]; af[7] = (__bf16)a1[3];
#pragma unroll
        for (int n = 0; n < 7; n++) {
            bf16x8 bf = *(bf16x8*)&lB[((size_t)q * 112 + n * 16 + ln) * 8];
            acc[n] = __builtin_amdgcn_mfma_f32_16x16x32_bf16(af, bf, acc[n], 0, 0, 0);
        }
        __syncthreads();
    }

    float s0 = 0.f, s1 = 0.f, s2 = 0.f, s3 = 0.f;
#pragma unroll
    for (int n = 0; n < 7; n++) {
        int j = n * 16 + ln;
        if (j < AA1) {
            float bj = b1[j], wj = w2[j];
            s0 += tanhf(acc[n][0] + bj) * wj;
            s1 += tanhf(acc[n][1] + bj) * wj;
            s2 += tanhf(acc[n][2] + bj) * wj;
            s3 += tanhf(acc[n][3] + bj) * wj;
        }
    }
#pragma unroll
    for (int off = 1; off < 16; off <<= 1) {
        s0 += __shfl_xor(s0, off);
        s1 += __shfl_xor(s1, off);
        s2 += __shfl_xor(s2, off);
        s3 += __shfl_xor(s3, off);
    }
    if (ln == 0) {
        float bb = b2[0];
        int base = tok0 + w * 16 + q * 4;
        token_att[base + 0] = 1.f / (1.f + expf(-(s0 + bb)));
        token_att[base + 1] = 1.f / (1.f + expf(-(s1 + bb)));
        token_att[base + 2] = 1.f / (1.f + expf(-(s2 + bb)));
        token_att[base + 3] = 1.f / (1.f + expf(-(s3 + bb)));
    }
}

// ---------------------------------------------------------------------------
// Kernel 2: scan/segmax/mask + stats + compaction -> ws
// stats[b] = (tokl, maxm, minone, slab); cw/cs compacted nonzeros; inv = 1/att
// ---------------------------------------------------------------------------
__global__ __launch_bounds__(512) void k_mask(
        const float* __restrict__ token_att, const float* __restrict__ labels,
        const int* __restrict__ offm, float* __restrict__ masked_out,
        float* __restrict__ cw_g, short* __restrict__ cs_g,
        int* __restrict__ nnz_g, float* __restrict__ inv_g,
        float4* __restrict__ stats_g) {
    __shared__ int smax[512];
    __shared__ int wscan[8];
    __shared__ int wscan2[8];
    __shared__ float wred[5][8];

    const int b = blockIdx.x, s = threadIdx.x;
    const int lane = s & 63, wv = s >> 6;
    const int ns = (offm[(b * SS + s) * 2] == 0) ? 1 : 0;

    int v = ns;
#pragma unroll
    for (int off = 1; off < 64; off <<= 1) {
        int o = __shfl_up(v, off);
        if (lane >= off) v += o;
    }
    if (lane == 63) wscan[wv] = v;
    smax[s] = 0;
    __syncthreads();
    int woff = 0;
    for (int i = 0; i < 8; i++) woff += (i < wv) ? wscan[i] : 0;
    const int seg = max(v + woff - 1, 0);

    const float ta = token_att[b * SS + s];
    atomicMax(&smax[seg], __float_as_int(ta));   // sigmoid > 0: int order ok
    __syncthreads();

    const float wa = ns ? __int_as_float(smax[seg]) : 0.f;
    const float lab = labels[b * SS + s];
    const float m = (lab != -1.f && ns) ? wa : 0.f;
    masked_out[b * SS + s] = m;

    const float zl = (lab != -1.f) ? lab : 0.f;
    const float tl = (m - zl) * (m - zl);
    const float ones = (m == 0.f) ? 1.f : m;

    float r0 = m, r1 = tl, r2 = m, r3 = ones, r4 = lab;
#pragma unroll
    for (int off = 32; off > 0; off >>= 1) {
        r0 += __shfl_xor(r0, off);
        r1 += __shfl_xor(r1, off);
        r2 = fmaxf(r2, __shfl_xor(r2, off));
        r3 = fminf(r3, __shfl_xor(r3, off));
        r4 = fmaxf(r4, __shfl_xor(r4, off));
    }
    if (lane == 0) {
        wred[0][wv] = r0; wred[1][wv] = r1; wred[2][wv] = r2;
        wred[3][wv] = r3; wred[4][wv] = r4;
    }

    const int nz = (m != 0.f) ? 1 : 0;
    int v2 = nz;
#pragma unroll
    for (int off = 1; off < 64; off <<= 1) {
        int o = __shfl_up(v2, off);
        if (lane >= off) v2 += o;
    }
    if (lane == 63) wscan2[wv] = v2;
    __syncthreads();

    int woff2 = 0;
    for (int i = 0; i < 8; i++) woff2 += (i < wv) ? wscan2[i] : 0;
    if (nz) {
        int pos = v2 + woff2 - 1;
        cw_g[b * SS + pos] = m;
        cs_g[b * SS + pos] = (short)s;
    }
    if (s == 0) {
        float att = 0.f, tokl = 0.f, maxm = -1e30f, minone = 1e30f, slab = -1e30f;
        int nnz = 0;
        for (int i = 0; i < 8; i++) {
            att += wred[0][i]; tokl += wred[1][i];
            maxm = fmaxf(maxm, wred[2][i]);
            minone = fminf(minone, wred[3][i]);
            slab = fmaxf(slab, wred[4][i]);
            nnz += wscan2[i];
        }
        nnz_g[b] = nnz;
        inv_g[b] = 1.f / att;
        stats_g[b] = make_float4(tokl, maxm, minone, slab);
    }
}

// ---------------------------------------------------------------------------
// Kernel 3: pooled[b,h] = inv[b] * sum_i cw[i]*hs[b,cs[i],h]
// grid (BB, 3): block owns 256 h-channels; 8 independent accumulators so 8
// global loads are in flight per waitcnt (latency /8).
// ---------------------------------------------------------------------------
__global__ __launch_bounds__(256) void k_pool(
        const float* __restrict__ hs, const float* __restrict__ cw_g,
        const short* __restrict__ cs_g, const int* __restrict__ nnz_g,
        const float* __restrict__ inv_g, float* __restrict__ pooled) {
    __shared__ float w[SS];
    __shared__ short idx[SS];
    const int b = blockIdx.x, g = blockIdx.y, tid = threadIdx.x;
    const int nnz = nnz_g[b];
    for (int i = tid; i < nnz; i += 256) {
        w[i] = cw_g[b * SS + i];
        idx[i] = cs_g[b * SS + i];
    }
    __syncthreads();
    const int h = g * 256 + tid;
    const float* hsb = hs + (size_t)b * SS * HH + h;
    float a0 = 0.f, a1 = 0.f, a2 = 0.f, a3 = 0.f;
    float a4 = 0.f, a5 = 0.f, a6 = 0.f, a7 = 0.f;
    int i = 0;
    for (; i + 8 <= nnz; i += 8) {
        a0 += hsb[(size_t)idx[i + 0] * HH] * w[i + 0];
        a1 += hsb[(size_t)idx[i + 1] * HH] * w[i + 1];
        a2 += hsb[(size_t)idx[i + 2] * HH] * w[i + 2];
        a3 += hsb[(size_t)idx[i + 3] * HH] * w[i + 3];
        a4 += hsb[(size_t)idx[i + 4] * HH] * w[i + 4];
        a5 += hsb[(size_t)idx[i + 5] * HH] * w[i + 5];
        a6 += hsb[(size_t)idx[i + 6] * HH] * w[i + 6];
        a7 += hsb[(size_t)idx[i + 7] * HH] * w[i + 7];
    }
    for (; i < nnz; i++) a0 += hsb[(size_t)idx[i] * HH] * w[i];
    float acc = ((a0 + a1) + (a2 + a3)) + ((a4 + a5) + (a6 + a7));
    pooled[b * HH + h] = acc * inv_g[b];
}

// ---------------------------------------------------------------------------
// Kernel 4: sentence MLP + sigmoid + per-row loss atomics
// ---------------------------------------------------------------------------
__global__ __launch_bounds__(320) void k_sentfinal(
        const float* __restrict__ pooled, const float4* __restrict__ stats_g,
        const float* __restrict__ sw1, const float* __restrict__ sb1,
        const float* __restrict__ sw2, const float* __restrict__ sb2,
        float* __restrict__ sent_out, float* __restrict__ out) {
    __shared__ float p[HH];
    __shared__ float wsum[5];
    const int b = blockIdx.x, tid = threadIdx.x;
    const int lane = tid & 63, wv = tid >> 6;
    for (int i = tid; i < HH; i += 320) p[i] = pooled[b * HH + i];
    __syncthreads();

    float tt = 0.f;
    if (tid < CC1) {
        float z = sb1[tid];
#pragma unroll 8
        for (int k = 0; k < HH; k++) z += p[k] * sw1[k * CC1 + tid];
        tt = tanhf(z) * sw2[tid];
    }
#pragma unroll
    for (int off = 32; off > 0; off >>= 1) tt += __shfl_xor(tt, off);
    if (lane == 0) wsum[wv] = tt;
    __syncthreads();
    if (tid == 0) {
        float zsum = wsum[0] + wsum[1] + wsum[2] + wsum[3] + wsum[4];
        float sv = 1.f / (1.f + expf(-(zsum + sb2[0])));
        sent_out[b] = sv;
        float4 st = stats_g[b];             // tokl, maxm, minone, slab
        float vs = sv - st.w; vs *= vs;
        float ra = st.z * st.z;
        float rb = st.y - st.w; rb *= rb;
        atomicAdd(&out[1], vs);
        atomicAdd(&out[2], st.x);
        atomicAdd(&out[3], ra);
        atomicAdd(&out[4], rb);
        atomicAdd(&out[0], vs + st.x + 0.01f * (ra + rb));
    }
}

extern "C" void kernel_launch(void* const* d_in, const int* in_sizes, int n_in,
                              void* d_out, int out_size, void* d_ws, size_t ws_size,
                              hipStream_t stream) {
    const float* hs  = (const float*)d_in[0];
    const float* w1  = (const float*)d_in[1];
    const float* b1  = (const float*)d_in[2];
    const float* w2  = (const float*)d_in[3];
    const float* b2  = (const float*)d_in[4];
    const float* sw1 = (const float*)d_in[5];
    const float* sb1 = (const float*)d_in[6];
    const float* sw2 = (const float*)d_in[7];
    const float* sb2 = (const float*)d_in[8];
    const float* labels = (const float*)d_in[9];
    const int*   offm   = (const int*)d_in[10];

    float* out = (float*)d_out;
    float* ws  = (float*)d_ws;

    // ws layout (float units)
    float*  token_att = ws;                       // 32768
    __bf16* w1i    = (__bf16*)(ws + 32768);       // 86016 bf16 = 43008 f
    float*  cw     = ws + 32768 + 43008;          // 32768
    short*  cs     = (short*)(cw + 32768);        // 32768 shorts = 16384 f
    int*    nnz    = (int*)(cw + 32768 + 16384);  // 64
    float*  inv    = (float*)(nnz + 64);          // 64
    float4* stats  = (float4*)(inv + 64);         // 64 float4 = 256 f
    float*  pooled = inv + 64 + 256;              // 49152

    // d_out layout: [total, sentence_loss, token_loss, reg_a, reg_b,
    //                masked(64*512), sent(64)]
    float* masked_out = out + 5;
    float* sent_out   = out + 5 + BB * SS;

    hipMemsetAsync(out, 0, 5 * sizeof(float), stream);
    hipLaunchKernelGGL(k_prep, dim3(336), dim3(256), 0, stream, w1, w1i);
    hipLaunchKernelGGL(k_token_att, dim3(512), dim3(256), 0, stream,
                       hs, w1i, b1, w2, b2, token_att);
    hipLaunchKernelGGL(k_mask, dim3(BB), dim3(512), 0, stream,
                       token_att, labels, offm, masked_out,
                       cw, cs, nnz, inv, stats);
    hipLaunchKernelGGL(k_pool, dim3(BB, 3), dim3(256), 0, stream,
                       hs, cw, cs, nnz, inv, pooled);
    hipLaunchKernelGGL(k_sentfinal, dim3(BB), dim3(320), 0, stream,
                       pooled, stats, sw1, sb1, sw2, sb2, sent_out, out);
}

// Round 6
// 246.580 us; speedup vs baseline: 1.0490x; 1.0012x over previous
//
#include <hip/hip_runtime.h>
#include <math.h>

#define BB 64
#define SS 512
#define HH 768
#define AA1 100
#define CC1 300

typedef __bf16 bf16x8 __attribute__((ext_vector_type(8)));
typedef float f32x4 __attribute__((ext_vector_type(4)));

#ifndef __has_builtin
#define __has_builtin(x) 0
#endif
#if __has_builtin(__builtin_amdgcn_global_load_lds)
#define HAVE_GLL 1
#else
#define HAVE_GLL 0
#endif

#define AS1 __attribute__((address_space(1)))
#define AS3 __attribute__((address_space(3)))

// ---------------------------------------------------------------------------
// Prep: B image for async staging (chunk-major per 32-K tile, zero-pad j>=100)
//   w1i[((kt*4+q)*112 + j)*8 + e] = bf16(w1[(kt*32+q*8+e)*100 + j])
// ---------------------------------------------------------------------------
__global__ __launch_bounds__(256) void k_prep(const float* __restrict__ w1,
                                              __bf16* __restrict__ w1i) {
    int idx = blockIdx.x * 256 + threadIdx.x;   // 86016 = 336*256
    int j = idx % 112;
    int r = idx / 112;
    int e = r & 7, g = r >> 3;  // g = kt*4 + q
    int k = (g >> 2) * 32 + (g & 3) * 8 + e;
    float v = (j < AA1) ? w1[k * AA1 + j] : 0.f;
    w1i[((size_t)g * 112 + j) * 8 + e] = (__bf16)v;
}

// ---------------------------------------------------------------------------
// Kernel 1: token attention, bf16 MFMA 16x16x32, 128-token blocks.
// Wave w: tokens w*32..w*32+31 (2 M-tiles) x 7 N-tiles -> 14 MFMA / K-iter.
// A staged fp32 via global_load_lds w/ XOR chunk swizzle; B from k_prep image.
// ---------------------------------------------------------------------------
__global__ __launch_bounds__(256) void k_token_att(
        const float* __restrict__ hs, const __bf16* __restrict__ w1i,
        const float* __restrict__ b1, const float* __restrict__ w2,
        const float* __restrict__ b2, float* __restrict__ token_att) {
    __shared__ __attribute__((aligned(16))) float lA[4096];   // 128 tok x 32 k fp32
    __shared__ __attribute__((aligned(16))) __bf16 lB[3584];  // [q][j] chunks

    const int tid = threadIdx.x;
    const int tok0 = blockIdx.x * 128;
    const int w = tid >> 6, lane = tid & 63;
    const int q = lane >> 4, ln = lane & 15;
    const int t0 = w * 32 + ln;          // tile 2w token row
    const int t1 = t0 + 16;              // tile 2w+1 token row

    f32x4 acc0[7], acc1[7];
#pragma unroll
    for (int n = 0; n < 7; n++) {
        acc0[n] = (f32x4){0.f, 0.f, 0.f, 0.f};
        acc1[n] = (f32x4){0.f, 0.f, 0.f, 0.f};
    }

    const int p0 = (2 * q) ^ (ln & 7);
    const int p1 = (2 * q + 1) ^ (ln & 7);

    for (int kt = 0; kt < 24; kt++) {
        const int ko = kt * 32;
        // ---- A: 1024 chunks (16B): chunk i -> token i>>3, glob chunk (i&7)^(tok&7)
#pragma unroll
        for (int it = 0; it < 4; it++) {
            int i = tid + it * 256;
            int tt = i >> 3, c = (i & 7) ^ (tt & 7);
            const float* g = hs + (size_t)(tok0 + tt) * HH + ko + c * 4;
#if HAVE_GLL
            __builtin_amdgcn_global_load_lds((AS1 void*)g,
                    (AS3 void*)(lA + (it * 256 + w * 64) * 4), 16, 0, 0);
#else
            *(f32x4*)&lA[i * 4] = *(const f32x4*)g;
#endif
        }
        // ---- B: 448 chunks
        {
            const __bf16* gb0 = w1i + (size_t)kt * 3584 + (size_t)tid * 8;
#if HAVE_GLL
            __builtin_amdgcn_global_load_lds((AS1 void*)gb0,
                    (AS3 void*)(lB + (w * 64) * 8), 16, 0, 0);
            if (w < 3) {
                const __bf16* gb1 = w1i + (size_t)kt * 3584 + (size_t)(tid + 256) * 8;
                __builtin_amdgcn_global_load_lds((AS1 void*)gb1,
                        (AS3 void*)(lB + (256 + w * 64) * 8), 16, 0, 0);
            }
#else
            *(bf16x8*)&lB[(size_t)tid * 8] = *(const bf16x8*)gb0;
            if (tid < 192) {
                const __bf16* gb1 = w1i + (size_t)kt * 3584 + (size_t)(tid + 256) * 8;
                *(bf16x8*)&lB[(size_t)(tid + 256) * 8] = *(const bf16x8*)gb1;
            }
#endif
        }
        __syncthreads();
        // ---- A fragments (fp32 -> bf16)
        f32x4 a00 = *(f32x4*)&lA[(t0 * 8 + p0) * 4];
        f32x4 a01 = *(f32x4*)&lA[(t0 * 8 + p1) * 4];
        f32x4 a10 = *(f32x4*)&lA[(t1 * 8 + p0) * 4];
        f32x4 a11 = *(f32x4*)&lA[(t1 * 8 + p1) * 4];
        bf16x8 af0, af1;
#pragma unroll
        for (int e = 0; e < 4; e++) {
            af0[e] = (__bf16)a00[e]; af0[e + 4] = (__bf16)a01[e];
            af1[e] = (__bf16)a10[e]; af1[e + 4] = (__bf16)a11[e];
        }
#pragma unroll
        for (int n = 0; n < 7; n++) {
            bf16x8 bf = *(bf16x8*)&lB[((size_t)q * 112 + n * 16 + ln) * 8];
            acc0[n] = __builtin_amdgcn_mfma_f32_16x16x32_bf16(af0, bf, acc0[n], 0, 0, 0);
            acc1[n] = __builtin_amdgcn_mfma_f32_16x16x32_bf16(af1, bf, acc1[n], 0, 0, 0);
        }
        __syncthreads();
    }

    // epilogue per tile: col j = n*16+ln, token = base + q*4 + reg
    float s0 = 0.f, s1 = 0.f, s2 = 0.f, s3 = 0.f;
    float u0 = 0.f, u1 = 0.f, u2 = 0.f, u3 = 0.f;
#pragma unroll
    for (int n = 0; n < 7; n++) {
        int j = n * 16 + ln;
        if (j < AA1) {
            float bj = b1[j], wj = w2[j];
            s0 += tanhf(acc0[n][0] + bj) * wj;
            s1 += tanhf(acc0[n][1] + bj) * wj;
            s2 += tanhf(acc0[n][2] + bj) * wj;
            s3 += tanhf(acc0[n][3] + bj) * wj;
            u0 += tanhf(acc1[n][0] + bj) * wj;
            u1 += tanhf(acc1[n][1] + bj) * wj;
            u2 += tanhf(acc1[n][2] + bj) * wj;
            u3 += tanhf(acc1[n][3] + bj) * wj;
        }
    }
#pragma unroll
    for (int off = 1; off < 16; off <<= 1) {
        s0 += __shfl_xor(s0, off); s1 += __shfl_xor(s1, off);
        s2 += __shfl_xor(s2, off); s3 += __shfl_xor(s3, off);
        u0 += __shfl_xor(u0, off); u1 += __shfl_xor(u1, off);
        u2 += __shfl_xor(u2, off); u3 += __shfl_xor(u3, off);
    }
    if (ln == 0) {
        float bb = b2[0];
        int base0 = tok0 + w * 32 + q * 4;
        int base1 = base0 + 16;
        token_att[base0 + 0] = 1.f / (1.f + expf(-(s0 + bb)));
        token_att[base0 + 1] = 1.f / (1.f + expf(-(s1 + bb)));
        token_att[base0 + 2] = 1.f / (1.f + expf(-(s2 + bb)));
        token_att[base0 + 3] = 1.f / (1.f + expf(-(s3 + bb)));
        token_att[base1 + 0] = 1.f / (1.f + expf(-(u0 + bb)));
        token_att[base1 + 1] = 1.f / (1.f + expf(-(u1 + bb)));
        token_att[base1 + 2] = 1.f / (1.f + expf(-(u2 + bb)));
        token_att[base1 + 3] = 1.f / (1.f + expf(-(u3 + bb)));
    }
}

// ---------------------------------------------------------------------------
// Kernel 2: scan/segmax/mask + stats + compaction -> ws. Block 0 zeroes
// out[0..5) (atomicAdd targets of k_poolsent, which launches after).
// ---------------------------------------------------------------------------
__global__ __launch_bounds__(512) void k_mask(
        const float* __restrict__ token_att, const float* __restrict__ labels,
        const int* __restrict__ offm, float* __restrict__ masked_out,
        float* __restrict__ cw_g, short* __restrict__ cs_g,
        int* __restrict__ nnz_g, float* __restrict__ inv_g,
        float4* __restrict__ stats_g, float* __restrict__ out) {
    __shared__ int smax[512];
    __shared__ int wscan[8];
    __shared__ int wscan2[8];
    __shared__ float wred[5][8];

    const int b = blockIdx.x, s = threadIdx.x;
    const int lane = s & 63, wv = s >> 6;
    if (b == 0 && s < 5) out[s] = 0.f;
    const int ns = (offm[(b * SS + s) * 2] == 0) ? 1 : 0;

    int v = ns;
#pragma unroll
    for (int off = 1; off < 64; off <<= 1) {
        int o = __shfl_up(v, off);
        if (lane >= off) v += o;
    }
    if (lane == 63) wscan[wv] = v;
    smax[s] = 0;
    __syncthreads();
    int woff = 0;
    for (int i = 0; i < 8; i++) woff += (i < wv) ? wscan[i] : 0;
    const int seg = max(v + woff - 1, 0);

    const float ta = token_att[b * SS + s];
    atomicMax(&smax[seg], __float_as_int(ta));   // sigmoid > 0: int order ok
    __syncthreads();

    const float wa = ns ? __int_as_float(smax[seg]) : 0.f;
    const float lab = labels[b * SS + s];
    const float m = (lab != -1.f && ns) ? wa : 0.f;
    masked_out[b * SS + s] = m;

    const float zl = (lab != -1.f) ? lab : 0.f;
    const float tl = (m - zl) * (m - zl);
    const float ones = (m == 0.f) ? 1.f : m;

    float r0 = m, r1 = tl, r2 = m, r3 = ones, r4 = lab;
#pragma unroll
    for (int off = 32; off > 0; off >>= 1) {
        r0 += __shfl_xor(r0, off);
        r1 += __shfl_xor(r1, off);
        r2 = fmaxf(r2, __shfl_xor(r2, off));
        r3 = fminf(r3, __shfl_xor(r3, off));
        r4 = fmaxf(r4, __shfl_xor(r4, off));
    }
    if (lane == 0) {
        wred[0][wv] = r0; wred[1][wv] = r1; wred[2][wv] = r2;
        wred[3][wv] = r3; wred[4][wv] = r4;
    }

    const int nz = (m != 0.f) ? 1 : 0;
    int v2 = nz;
#pragma unroll
    for (int off = 1; off < 64; off <<= 1) {
        int o = __shfl_up(v2, off);
        if (lane >= off) v2 += o;
    }
    if (lane == 63) wscan2[wv] = v2;
    __syncthreads();

    int woff2 = 0;
    for (int i = 0; i < 8; i++) woff2 += (i < wv) ? wscan2[i] : 0;
    if (nz) {
        int pos = v2 + woff2 - 1;
        cw_g[b * SS + pos] = m;
        cs_g[b * SS + pos] = (short)s;
    }
    if (s == 0) {
        float att = 0.f, tokl = 0.f, maxm = -1e30f, minone = 1e30f, slab = -1e30f;
        int nnz = 0;
        for (int i = 0; i < 8; i++) {
            att += wred[0][i]; tokl += wred[1][i];
            maxm = fmaxf(maxm, wred[2][i]);
            minone = fminf(minone, wred[3][i]);
            slab = fmaxf(slab, wred[4][i]);
            nnz += wscan2[i];
        }
        nnz_g[b] = nnz;
        inv_g[b] = 1.f / att;
        stats_g[b] = make_float4(tokl, maxm, minone, slab);
    }
}

// ---------------------------------------------------------------------------
// Kernel 3 (fused): pooling over compacted list (8 independent accumulators,
// both h-halves per thread) + sentence MLP + sigmoid + loss atomics.
// One block (512 threads) per batch row.
// ---------------------------------------------------------------------------
__global__ __launch_bounds__(512) void k_poolsent(
        const float* __restrict__ hs, const float* __restrict__ cw_g,
        const short* __restrict__ cs_g, const int* __restrict__ nnz_g,
        const float* __restrict__ inv_g, const float4* __restrict__ stats_g,
        const float* __restrict__ sw1, const float* __restrict__ sb1,
        const float* __restrict__ sw2, const float* __restrict__ sb2,
        float* __restrict__ sent_out, float* __restrict__ out) {
    __shared__ float w[SS];
    __shared__ short idx[SS];
    __shared__ float pool[HH];
    __shared__ float wsum[8];

    const int b = blockIdx.x, tid = threadIdx.x;
    const int lane = tid & 63, wv = tid >> 6;
    const int nnz = nnz_g[b];
    if (tid < nnz) { w[tid] = cw_g[b * SS + tid]; idx[tid] = cs_g[b * SS + tid]; }
    __syncthreads();

    const float* hsb = hs + (size_t)b * SS * HH;
    const bool hi = (tid < 256);
    float a[8], c[8];
#pragma unroll
    for (int u = 0; u < 8; u++) { a[u] = 0.f; c[u] = 0.f; }
    int i = 0;
    for (; i + 8 <= nnz; i += 8) {
#pragma unroll
        for (int u = 0; u < 8; u++)
            a[u] += hsb[(size_t)idx[i + u] * HH + tid] * w[i + u];
        if (hi) {
#pragma unroll
            for (int u = 0; u < 8; u++)
                c[u] += hsb[(size_t)idx[i + u] * HH + 512 + tid] * w[i + u];
        }
    }
    for (; i < nnz; i++) {
        a[0] += hsb[(size_t)idx[i] * HH + tid] * w[i];
        if (hi) c[0] += hsb[(size_t)idx[i] * HH + 512 + tid] * w[i];
    }
    const float inv = inv_g[b];
    pool[tid] = (((a[0] + a[1]) + (a[2] + a[3])) + ((a[4] + a[5]) + (a[6] + a[7]))) * inv;
    if (hi)
        pool[512 + tid] = (((c[0] + c[1]) + (c[2] + c[3])) + ((c[4] + c[5]) + (c[6] + c[7]))) * inv;
    __syncthreads();

    // ---- sentence MLP: thread = hidden unit (tid < 300)
    float tt = 0.f;
    if (tid < CC1) {
        float z = sb1[tid];
#pragma unroll 8
        for (int k = 0; k < HH; k++) z += pool[k] * sw1[k * CC1 + tid];
        tt = tanhf(z) * sw2[tid];
    }
#pragma unroll
    for (int off = 32; off > 0; off >>= 1) tt += __shfl_xor(tt, off);
    if (lane == 0) wsum[wv] = tt;
    __syncthreads();
    if (tid == 0) {
        float zsum = wsum[0] + wsum[1] + wsum[2] + wsum[3] + wsum[4];
        float sv = 1.f / (1.f + expf(-(zsum + sb2[0])));
        sent_out[b] = sv;
        float4 st = stats_g[b];             // tokl, maxm, minone, slab
        float vs = sv - st.w; vs *= vs;
        float ra = st.z * st.z;
        float rb = st.y - st.w; rb *= rb;
        atomicAdd(&out[1], vs);
        atomicAdd(&out[2], st.x);
        atomicAdd(&out[3], ra);
        atomicAdd(&out[4], rb);
        atomicAdd(&out[0], vs + st.x + 0.01f * (ra + rb));
    }
}

extern "C" void kernel_launch(void* const* d_in, const int* in_sizes, int n_in,
                              void* d_out, int out_size, void* d_ws, size_t ws_size,
                              hipStream_t stream) {
    const float* hs  = (const float*)d_in[0];
    const float* w1  = (const float*)d_in[1];
    const float* b1  = (const float*)d_in[2];
    const float* w2  = (const float*)d_in[3];
    const float* b2  = (const float*)d_in[4];
    const float* sw1 = (const float*)d_in[5];
    const float* sb1 = (const float*)d_in[6];
    const float* sw2 = (const float*)d_in[7];
    const float* sb2 = (const float*)d_in[8];
    const float* labels = (const float*)d_in[9];
    const int*   offm   = (const int*)d_in[10];

    float* out = (float*)d_out;
    float* ws  = (float*)d_ws;

    // ws layout (float units)
    float*  token_att = ws;                       // 32768
    __bf16* w1i    = (__bf16*)(ws + 32768);       // 86016 bf16 = 43008 f
    float*  cw     = ws + 32768 + 43008;          // 32768
    short*  cs     = (short*)(cw + 32768);        // 32768 shorts = 16384 f
    int*    nnz    = (int*)(cw + 32768 + 16384);  // 64
    float*  inv    = (float*)(nnz + 64);          // 64
    float4* stats  = (float4*)(inv + 64);         // 64 float4

    // d_out layout: [total, sentence_loss, token_loss, reg_a, reg_b,
    //                masked(64*512), sent(64)]
    float* masked_out = out + 5;
    float* sent_out   = out + 5 + BB * SS;

    hipLaunchKernelGGL(k_prep, dim3(336), dim3(256), 0, stream, w1, w1i);
    hipLaunchKernelGGL(k_token_att, dim3(256), dim3(256), 0, stream,
                       hs, w1i, b1, w2, b2, token_att);
    hipLaunchKernelGGL(k_mask, dim3(BB), dim3(512), 0, stream,
                       token_att, labels, offm, masked_out,
                       cw, cs, nnz, inv, stats, out);
    hipLaunchKernelGGL(k_poolsent, dim3(BB), dim3(512), 0, stream,
                       hs, cw, cs, nnz, inv, stats,
                       sw1, sb1, sw2, sb2, sent_out, out);
}